// Round 5
// baseline (40.526 us; speedup 1.0000x reference)
//
#include <hip/hip_runtime.h>

namespace {
constexpr int kM = 4, kJ = 2, kI = 3, kL = 2, kW = 9;
constexpr float kInvLn2 = 1.4426950408889634f;

typedef float v2f __attribute__((ext_vector_type(2)));  // -> v_pk_*_f32

__device__ __forceinline__ float fexp2(float x) { return __builtin_amdgcn_exp2f(x); }

// dp layout (80 floats), per m (18 floats at m*18), j-packed {j0,j1} pairs:
//   [An, B0n, B1n, w0n, w1n, C00, C01, C10, C11]
// where An/B*n/w*n are the quad coeffs of  msN = -ms/ln2  (negated, log2-scaled):
//   msN = An + s0*(B0n + w0n*s0) + s1*(B1n + w1n*s1)
// C (head∘body matrix, gavg-folded) unscaled. D[m][l] at 72 + m*2 + l.
__global__ void prep_kernel(const float* __restrict__ constants,
                            const float* __restrict__ gammas,
                            const float* __restrict__ W_body,
                            const float* __restrict__ b_body,
                            const float* __restrict__ W_head,
                            const float* __restrict__ b_head,
                            float* __restrict__ dp) {
  const int t = threadIdx.x;
  if (t < 8) {
    const int mj = t, m = t >> 1, j = t & 1;
    const float g0 = fminf(fmaxf(gammas[mj * kL + 0], 0.f), 1.f);
    const float g1 = fminf(fmaxf(gammas[mj * kL + 1], 0.f), 1.f);
    const float w0 = 1.f - g0, w1 = 1.f - g1;
    const float c0 = constants[mj * kL + 0], c1 = constants[mj * kL + 1];
    const float gavg = 0.5f * (g0 + g1);
    float* base = dp + m * 18;
    base[0 * 2 + j] = -(w0 * c0 * c0 + w1 * c1 * c1) * kInvLn2;  // An
    base[1 * 2 + j] = 2.f * w0 * c0 * kInvLn2;                   // B0n
    base[2 * 2 + j] = 2.f * w1 * c1 * kInvLn2;                   // B1n
    base[3 * 2 + j] = -w0 * kInvLn2;                             // w0n
    base[4 * 2 + j] = -w1 * kInvLn2;                             // w1n
    for (int l = 0; l < kL; ++l)
      for (int lp = 0; lp < kL; ++lp) {
        float acc = 0.f;
        for (int i = 0; i < kI; ++i)
          acc += W_head[(m * kL + l) * kI + i] * W_body[(mj * kI + i) * kL + lp];
        base[(5 + l * kL + lp) * 2 + j] = gavg * acc;            // C[l][lp]
      }
  } else if (t < 12) {
    const int m = t - 8;
    for (int l = 0; l < kL; ++l) {
      float d = b_head[m * kL + l];
      for (int j = 0; j < kJ; ++j) {
        const int mj = m * kJ + j;
        const float g0 = fminf(fmaxf(gammas[mj * kL + 0], 0.f), 1.f);
        const float g1 = fminf(fmaxf(gammas[mj * kL + 1], 0.f), 1.f);
        const float gavg = 0.5f * (g0 + g1);
        float acc = 0.f;
        for (int i = 0; i < kI; ++i)
          acc += W_head[(m * kL + l) * kI + i] * b_body[mj * kI + i];
        d += gavg * acc;
      }
      dp[72 + m * kL + l] = d;
    }
  }
}

// 2 batch elements per thread: loads are 9x dwordx4 (16B/lane, 16-aligned:
// pair base = p*144B), stores 9x float2. Params read via uniform (scalar)
// loads straight from dp — no LDS, no barrier.
__global__ __launch_bounds__(256) void algelogic_main(
    const float* __restrict__ state, const float* __restrict__ dp,
    float* __restrict__ out) {
  const int p = blockIdx.x * 256 + threadIdx.x;   // pair index
  const float4* sq = reinterpret_cast<const float4*>(state) + (size_t)p * 9;

  float4 sF[9];
#pragma unroll
  for (int k = 0; k < 9; ++k) sF[k] = sq[k];

  // sv(elem, w): {s0, s1} for that element/position — pure register aliasing
  auto sv = [&](int elem, int w) -> v2f {
    const int g = elem * 9 + w;          // compile-time under full unroll
    const float4 f = sF[g >> 1];
    v2f r;
    if (g & 1) { r.x = f.z; r.y = f.w; } else { r.x = f.x; r.y = f.y; }
    return r;
  };

  float Cs[2] = {0.f, 0.f}, X0[2] = {0.f, 0.f}, X1[2] = {0.f, 0.f}, K[2] = {0.f, 0.f};

#pragma unroll
  for (int m = 0; m < kM; ++m) {
    const float* P = dp + m * 18;
    v2f A, B0, B1, w0, w1, C00, C01, C10, C11;
    A.x = P[0]; A.y = P[1];  B0.x = P[2]; B0.y = P[3];
    B1.x = P[4]; B1.y = P[5]; w0.x = P[6]; w0.y = P[7];
    w1.x = P[8]; w1.y = P[9]; C00.x = P[10]; C00.y = P[11];
    C01.x = P[12]; C01.y = P[13]; C10.x = P[14]; C10.y = P[15];
    C11.x = P[16]; C11.y = P[17];
    const float D0 = dp[72 + m * 2 + 0], D1 = dp[72 + m * 2 + 1];

#pragma unroll
    for (int elem = 0; elem < 2; ++elem) {
      // msN[w] = -ms/ln2  (<= 0); no min-scan needed: exp2 of it is safe.
      v2f psum = {1e-35f, 1e-35f};   // guard: rcp never sees <2^-126
      v2f pb0 = {0.f, 0.f}, pb1 = {0.f, 0.f}, pmq = {0.f, 0.f};
#pragma unroll
      for (int w = 0; w < kW; ++w) {
        const v2f s = sv(elem, w);
        const v2f t0 = B0 + w0 * s.x;
        const v2f t1 = B1 + w1 * s.y;
        v2f msN = A + t0 * s.x;
        msN += t1 * s.y;
        v2f e; e.x = fexp2(msN.x); e.y = fexp2(msN.y);
        psum += e;
        pb0 += e * s.x;
        pb1 += e * s.y;
        pmq += e * msN;                // = -Σ e·ms/ln2
      }
      v2f rinv;
      rinv.x = __builtin_amdgcn_rcpf(psum.x);
      rinv.y = __builtin_amdgcn_rcpf(psum.y);
      const v2f bb0 = pb0 * rinv, bb1 = pb1 * rinv;
      const v2f mqv = pmq * rinv;
      const float conf = fexp2(mqv.x + mqv.y);   // exp2(-mq/ln2) = exp(-mq)

      const v2f t0 = C00 * bb0 + C01 * bb1;
      const v2f t1 = C10 * bb0 + C11 * bb1;
      const float r0 = D0 + t0.x + t0.y;
      const float r1 = D1 + t1.x + t1.y;

      Cs[elem] += conf;
      X0[elem] = fmaf(conf, r0, X0[elem]);
      X1[elem] = fmaf(conf, r1, X1[elem]);
      K[elem] = fmaf(conf, fmaf(r0, r0, r1 * r1), K[elem]);
    }
  }

  float* orow = out + (size_t)p * (2 * kW);
#pragma unroll
  for (int elem = 0; elem < 2; ++elem) {
    const float X02 = 2.f * X0[elem], X12 = 2.f * X1[elem];
    const float Csl = Cs[elem], Kl = K[elem];
#pragma unroll
    for (int w = 0; w < kW; w += 2) {   // emit as float2 pairs (8B aligned)
      float2 o;
      {
        const v2f s = sv(elem, w);
        const v2f q = s * s;
        o.x = fmaf(X02, s.x, fmaf(X12, s.y, fmaf(-Csl, q.x + q.y, -Kl)));
      }
      if (w + 1 < kW) {
        const v2f s = sv(elem, w + 1);
        const v2f q = s * s;
        o.y = fmaf(X02, s.x, fmaf(X12, s.y, fmaf(-Csl, q.x + q.y, -Kl)));
        *reinterpret_cast<float2*>(orow + elem * kW + w) = o;
      } else {
        orow[elem * kW + w] = o.x;     // odd tail (w=8): scalar store
      }
    }
  }
}
}  // namespace

extern "C" void kernel_launch(void* const* d_in, const int* in_sizes, int n_in,
                              void* d_out, int out_size, void* d_ws, size_t ws_size,
                              hipStream_t stream) {
  const float* state     = (const float*)d_in[0];
  const float* constants = (const float*)d_in[1];
  const float* gammas    = (const float*)d_in[2];
  const float* W_body    = (const float*)d_in[3];
  const float* b_body    = (const float*)d_in[4];
  const float* W_head    = (const float*)d_in[5];
  const float* b_head    = (const float*)d_in[6];
  float* out = (float*)d_out;
  float* dp  = (float*)d_ws;

  const int B = in_sizes[0] / (kW * kL);   // 1048576
  const int pairs = B / 2;                 // 524288
  hipLaunchKernelGGL(prep_kernel, dim3(1), dim3(64), 0, stream,
                     constants, gammas, W_body, b_body, W_head, b_head, dp);
  hipLaunchKernelGGL(algelogic_main, dim3(pairs / 256), dim3(256), 0, stream,
                     state, dp, out);
}